// Round 1
// baseline (1279.483 us; speedup 1.0000x reference)
//
#include <hip/hip_runtime.h>

#define Mc 512
#define Nc 1024
#define WRc 16
#define Bc 4096

// c2v state, layout [cn][b][j] -> fully coalesced per-step access.
// 512*4096*16 floats = 128 MB static device buffer (avoids relying on ws_size).
// Sweep 0 never reads it and sweep k writes every element before sweep k+1
// reads it, so no initialization is required (idempotent across launches).
__device__ float g_c2v[(size_t)Mc * Bc * WRc];

#define DPPI(old, src, ctrl) \
  __builtin_amdgcn_update_dpp((old), (src), (ctrl), 0xF, 0xF, false)

static __device__ __forceinline__ int imin(int a, int b) { return a < b ? a : b; }

__global__ __launch_bounds__(64, 4) void ldpc_kernel(
    const float* __restrict__ llr, const int* __restrict__ H,
    const int* __restrict__ iters_p, const int* __restrict__ cn_order,
    float* __restrict__ out) {
  const int tid = threadIdx.x;
  const int g = tid >> 4;    // batch sub-slot within wave (0..3)
  const int j = tid & 15;    // edge position within check node
  const int b0 = blockIdx.x * 4;
  const int b = b0 + g;

  __shared__ float vn[4][Nc];  // 16 KB: vn_llr for 4 batch elements

  // Load channel LLRs (coalesced).
  for (int i = tid; i < 4 * Nc; i += 64) {
    vn[i >> 10][i & (Nc - 1)] = llr[(size_t)(b0 + (i >> 10)) * Nc + (i & (Nc - 1))];
  }
  __syncthreads();

  const int T = iters_p[0] * Mc;

  // ---- depth-2 register prefetch pipeline (cn, H row, old c2v) ----
  int cn_a = cn_order[0];
  int idx_a = H[cn_a * WRc + j];
  float c2v_a = 0.0f;  // t=0 is in sweep 0: c2v == 0
  int cn_b = cn_a, idx_b = idx_a;
  float c2v_b = 0.0f;
  if (T > 1) {
    cn_b = cn_order[1 & (Mc - 1)];
    idx_b = H[cn_b * WRc + j];
    c2v_b = 0.0f;  // t=1 also sweep 0
  }

  const int INFB = 0x7F800000;

  for (int t = 0; t < T; ++t) {
    const int cn = cn_a;
    const int idx = idx_a;
    const float c2v_old = c2v_a;
    cn_a = cn_b; idx_a = idx_b; c2v_a = c2v_b;

    const int t2 = t + 2;
    if (t2 < T) {
      const int cn2 = cn_order[t2 & (Mc - 1)];
      cn_b = cn2;
      idx_b = H[cn2 * WRc + j];
      // reads target data written 512 steps ago by this same lane -> safe
      c2v_b = (t2 >= Mc) ? g_c2v[((size_t)cn2 * Bc + b) * WRc + j] : 0.0f;
    }

    // ---- the serial dependency chain ----
    const float v = vn[g][idx];          // LDS gather (depends on prev scatter)
    const float v2c = v - c2v_old;

    // |v2c| as int bits: non-negative floats order identically as ints.
    const int ab = __float_as_int(v2c) & 0x7FFFFFFF;

    // inclusive prefix-min over the 16-lane group (row_shr, shifted-in = +INF)
    int p = ab;
    p = imin(p, DPPI(INFB, p, 0x111));
    p = imin(p, DPPI(INFB, p, 0x112));
    p = imin(p, DPPI(INFB, p, 0x114));
    p = imin(p, DPPI(INFB, p, 0x118));
    // inclusive suffix-min (row_shl)
    int s = ab;
    s = imin(s, DPPI(INFB, s, 0x101));
    s = imin(s, DPPI(INFB, s, 0x102));
    s = imin(s, DPPI(INFB, s, 0x104));
    s = imin(s, DPPI(INFB, s, 0x108));
    // exclusive versions -> leave-one-out min (exact, ties/zeros correct)
    const int pe = DPPI(INFB, p, 0x111);
    const int se = DPPI(INFB, s, 0x101);
    const int loo = imin(pe, se);

    // sign parity: count of strictly-negative v2c in the group (row_ror sums)
    int ng = (v2c < 0.0f) ? 1 : 0;
    int tot = ng;
    tot += DPPI(0, tot, 0x121);
    tot += DPPI(0, tot, 0x122);
    tot += DPPI(0, tot, 0x124);
    tot += DPPI(0, tot, 0x128);
    const unsigned negp = (unsigned)(tot - ng) & 1u;

    // clip(sign*amp) == sign * min(amp, 20) since amp >= 0
    const float amp = fminf(__int_as_float(loo), 20.0f);
    const unsigned ncb = (unsigned)__float_as_int(amp) | (negp << 31);
    const float new_c2v = __uint_as_float(ncb);

    vn[g][idx] = v2c + new_c2v;                          // LDS scatter
    g_c2v[((size_t)cn * Bc + b) * WRc + j] = new_c2v;    // stream out (no dep)
  }

  // Output: hard decision (vn < 0) as float32, coalesced.
  for (int i = tid; i < 4 * Nc; i += 64) {
    const int gg = i >> 10, n = i & (Nc - 1);
    out[(size_t)(b0 + gg) * Nc + n] = (vn[gg][n] < 0.0f) ? 1.0f : 0.0f;
  }
}

extern "C" void kernel_launch(void* const* d_in, const int* in_sizes, int n_in,
                              void* d_out, int out_size, void* d_ws, size_t ws_size,
                              hipStream_t stream) {
  const float* llr = (const float*)d_in[0];
  const int* H = (const int*)d_in[1];
  const int* iters_p = (const int*)d_in[2];
  const int* cn_order = (const int*)d_in[3];
  float* out = (float*)d_out;
  ldpc_kernel<<<dim3(Bc / 4), dim3(64), 0, stream>>>(llr, H, iters_p, cn_order, out);
}

// Round 2
// 645.748 us; speedup vs baseline: 1.9814x; 1.9814x over previous
//
#include <hip/hip_runtime.h>

#define Mc 512
#define Nc 1024
#define WRc 16
#define Bc 4096

// c2v state indexed by step-slot s = t mod 512 (cn_order is a per-sweep
// permutation reused identically every sweep, so slot<->row is a fixed
// bijection). Layout [s][b][j] -> slot offset is a uniform scalar (s<<16
// elements), lane part (b*16+j) is loop-invariant. 128 MB static buffer;
// sweep 0 never reads it, so no init needed (idempotent across launches).
__device__ float g_c2v[(size_t)Mc * Bc * WRc];

#define DPPI(old, src, ctrl) \
  __builtin_amdgcn_update_dpp((old), (src), (ctrl), 0xF, 0xF, false)

static __device__ __forceinline__ int imin(int a, int b) { return a < b ? a : b; }

__global__ __launch_bounds__(64) void ldpc_kernel(
    const float* __restrict__ llr, const int* __restrict__ H,
    const int* __restrict__ iters_p, const int* __restrict__ cn_order,
    float* __restrict__ out) {
  const int tid = threadIdx.x;
  const int g = tid >> 4;    // batch sub-slot within wave (0..3)
  const int j = tid & 15;    // edge position within check node
  const int b0 = blockIdx.x * 4;
  const int b = b0 + g;

  __shared__ float vn[4][Nc];                 // 16 KB
  __shared__ unsigned short hp[Mc * WRc];     // 16 KB: H rows in cn_order order

  // Stage channel LLRs + permuted H (one-time; all traffic L2/L3-resident).
  for (int i = tid; i < 4 * Nc; i += 64)
    vn[i >> 10][i & (Nc - 1)] = llr[(size_t)(b0 + (i >> 10)) * Nc + (i & (Nc - 1))];
  for (int i = tid; i < Mc * WRc; i += 64)
    hp[i] = (unsigned short)H[cn_order[i >> 4] * WRc + (i & 15)];
  __syncthreads();

  const int T = iters_p[0] * Mc;              // always a multiple of 4
  float* const cptr = g_c2v + ((size_t)b * WRc + j);  // lane base; + (s<<16)

  const int INFB = 0x7F800000;

  // ---- pipeline prime ----
  int idx_cur = hp[j];                         // idx[0]
  int idx_nxt = hp[(1 & (Mc - 1)) * WRc + j];  // idx[1]
  int idx_f2  = hp[(2 & (Mc - 1)) * WRc + j];  // idx[2]
  float v = vn[g][idx_cur];                    // gather for t=0
  float c2vf[4] = {0.0f, 0.0f, 0.0f, 0.0f};    // c2v for t=0..3 (sweep 0 -> 0)

  for (int tb = 0; tb < T; tb += 4) {
#pragma unroll
    for (int k = 0; k < 4; ++k) {
      const int t = tb + k;

      // ---- serial chain ----
      const float v2c = v - c2vf[k];
      const int ab = __float_as_int(v2c) & 0x7FFFFFFF;

      // exclusive leave-one-out min via prefix/suffix int-min DPP scans
      int p = ab;
      p = imin(p, DPPI(INFB, p, 0x111));
      p = imin(p, DPPI(INFB, p, 0x112));
      p = imin(p, DPPI(INFB, p, 0x114));
      p = imin(p, DPPI(INFB, p, 0x118));
      int s = ab;
      s = imin(s, DPPI(INFB, s, 0x101));
      s = imin(s, DPPI(INFB, s, 0x102));
      s = imin(s, DPPI(INFB, s, 0x104));
      s = imin(s, DPPI(INFB, s, 0x108));
      const int pe = DPPI(INFB, p, 0x111);
      const int se = DPPI(INFB, s, 0x101);
      const int loo = imin(pe, se);

      // sign parity of the other 15 lanes (row_ror accumulation)
      int ng = (v2c < 0.0f) ? 1 : 0;
      int tot = ng;
      tot += DPPI(0, tot, 0x121);
      tot += DPPI(0, tot, 0x122);
      tot += DPPI(0, tot, 0x124);
      tot += DPPI(0, tot, 0x128);
      const unsigned negp = (unsigned)(tot - ng) & 1u;

      const float amp = fminf(__int_as_float(loo), 20.0f);
      const float nc = __uint_as_float((unsigned)__float_as_int(amp) | (negp << 31));

      vn[g][idx_cur] = v2c + nc;   // scatter (step t)
      v = vn[g][idx_nxt];          // gather (step t+1) — back-to-back, DS in-order

      // ---- off-chain work in the gather's latency shadow ----
      cptr[(size_t)(t & (Mc - 1)) << 16] = nc;            // c2v store (slot s)

      const int t4 = t + 4;                               // c2v prefetch, depth 4
      const float ld = cptr[(size_t)(t4 & (Mc - 1)) << 16];
      c2vf[k] = (t4 >= Mc) ? ld : 0.0f;

      idx_cur = idx_nxt;                                  // rotate idx pipeline
      idx_nxt = idx_f2;
      idx_f2 = hp[((t + 3) & (Mc - 1)) * WRc + j];        // idx prefetch, depth 3
    }
  }

  // Hard decision. Block = one wave, so no barrier needed (wave-synchronous).
  for (int i = tid; i < 4 * Nc; i += 64) {
    const int gg = i >> 10, n = i & (Nc - 1);
    out[(size_t)(b0 + gg) * Nc + n] = (vn[gg][n] < 0.0f) ? 1.0f : 0.0f;
  }
}

extern "C" void kernel_launch(void* const* d_in, const int* in_sizes, int n_in,
                              void* d_out, int out_size, void* d_ws, size_t ws_size,
                              hipStream_t stream) {
  const float* llr = (const float*)d_in[0];
  const int* H = (const int*)d_in[1];
  const int* iters_p = (const int*)d_in[2];
  const int* cn_order = (const int*)d_in[3];
  float* out = (float*)d_out;
  ldpc_kernel<<<dim3(Bc / 4), dim3(64), 0, stream>>>(llr, H, iters_p, cn_order, out);
}